// Round 9
// baseline (312.774 us; speedup 1.0000x reference)
//
#include <hip/hip_runtime.h>
#include <stdint.h>

#define N_NODES 40000
#define N_EDGES 640000
#define DD 128
#define LAYERS 3
#define SB 40  // scan blocks: 40 * 1024 >= N_NODES

typedef unsigned short u16;
typedef unsigned char u8;
typedef u16 u16x8 __attribute__((ext_vector_type(8)));
typedef short bf16x8 __attribute__((ext_vector_type(8)));
typedef float f32x4 __attribute__((ext_vector_type(4)));

__device__ inline u16 f2bf(float f) {  // RNE f32 -> bf16 (finite inputs)
  uint32_t u = __float_as_uint(f);
  return (u16)((u + 0x7fffu + ((u >> 16) & 1u)) >> 16);
}
__device__ inline float bflo2f(uint32_t u) { return __uint_as_float(u << 16); }
__device__ inline float bfhi2f(uint32_t u) { return __uint_as_float(u & 0xffff0000u); }
__device__ inline u8 f2fp8(float f) {  // f32 -> OCP e4m3fn via HW cvt
  return (u8)(__builtin_amdgcn_cvt_pk_fp8_f32(f, f, 0, false) & 0xFF);
}

// ---------------- setup: convert x, convert weights, count degrees, B sentinel ----------------
// psiF: [l][o=256][k=128]; phiT: [l][n=128][k=256]; dpT: [n=128][k=128]

__global__ __launch_bounds__(256) void setup_kernel(
    const float* __restrict__ x, const float* __restrict__ psi_w,
    const float* __restrict__ phi_w, const float* __restrict__ dp_w,
    const int* __restrict__ dst, u16* __restrict__ xb, u16* __restrict__ psiF,
    u16* __restrict__ phiT, u16* __restrict__ dpT, int* __restrict__ deg,
    u8* __restrict__ Bb) {
  int b = blockIdx.x, t = threadIdx.x;
  if (b < 2500) {  // convert x: 2500*256*8 = 5.12M elements
    size_t i = ((size_t)b * 256 + t) * 8;
    float4 v0 = *(const float4*)(x + i);
    float4 v1 = *(const float4*)(x + i + 4);
    u16x8 o;
    o[0] = f2bf(v0.x); o[1] = f2bf(v0.y); o[2] = f2bf(v0.z); o[3] = f2bf(v0.w);
    o[4] = f2bf(v1.x); o[5] = f2bf(v1.y); o[6] = f2bf(v1.z); o[7] = f2bf(v1.w);
    *(u16x8*)(xb + i) = o;
  } else if (b < 3332) {  // weights: 832*256 = 212992
    int idx = (b - 2500) * 256 + t;
    if (idx < 98304) {
      int l = idx >> 15, r = idx & 32767, o = r >> 7, k = r & 127;
      int kk = k + ((o >= 128) ? 128 : 0);
      psiF[idx] = f2bf(psi_w[l * 32768 + kk * 128 + (o & 127)]);
    } else if (idx < 196608) {
      int j = idx - 98304;
      int l = j >> 15, r = j & 32767, n = r >> 8, k = r & 255;
      phiT[j] = f2bf(phi_w[l * 32768 + k * 128 + n]);
    } else {
      int j = idx - 196608;
      int n = j >> 7, k = j & 127;
      dpT[j] = f2bf(dp_w[k * 128 + n]);
    }
  } else if (b < 5832) {  // count degrees: 2500*256 = 640000
    int e = (b - 3332) * 256 + t;
    atomicAdd(&deg[dst[e]], 1);
  } else {  // sentinel row: Bb[N_NODES][*] = 0xFE (-448 in e4m3fn) -> relu(A-448)=0
    if (t < 32) ((uint32_t*)(Bb + (size_t)N_NODES * DD))[t] = 0xFEFEFEFEu;
  }
}

// ---------------- scan (single dispatch): each block self-computes its prefix base ----------

__global__ __launch_bounds__(256) void scan_all(const int* __restrict__ deg,
                                                int* __restrict__ offs,
                                                float* __restrict__ inv_deg,
                                                int* __restrict__ csr) {
  __shared__ int red[256];
  int b = blockIdx.x, t = threadIdx.x;
  if (b == 0 && t < 16) csr[N_EDGES + t] = N_NODES;  // sentinel pad for batched gather
  int base_n = b * 1024;
  int loc = 0;
  for (int i = t * 4; i < base_n; i += 1024) {
    int4 v = *(const int4*)(deg + i);
    loc += v.x + v.y + v.z + v.w;
  }
  red[t] = loc;
  __syncthreads();
  for (int o = 128; o > 0; o >>= 1) {
    if (t < o) red[t] += red[t + o];
    __syncthreads();
  }
  int base = red[0];
  __syncthreads();
  int idx = base_n + t * 4;
  int4 v = {0, 0, 0, 0};
  if (idx < N_NODES) v = *(const int4*)(deg + idx);
  int ts = v.x + v.y + v.z + v.w;
  red[t] = ts;
  __syncthreads();
  for (int o = 1; o < 256; o <<= 1) {
    int u = (t >= o) ? red[t - o] : 0;
    __syncthreads();
    red[t] += u;
    __syncthreads();
  }
  int excl = base + red[t] - ts;
  if (idx < N_NODES) {
    int4 ov;
    ov.x = excl;
    ov.y = excl + v.x;
    ov.z = ov.y + v.y;
    ov.w = ov.z + v.z;
    *(int4*)(offs + idx) = ov;
    float4 iv;
    iv.x = 1.0f / (float)(v.x > 1 ? v.x : 1);
    iv.y = 1.0f / (float)(v.y > 1 ? v.y : 1);
    iv.z = 1.0f / (float)(v.z > 1 ? v.z : 1);
    iv.w = 1.0f / (float)(v.w > 1 ? v.w : 1);
    *(float4*)(inv_deg + idx) = iv;
  }
  if (b == SB - 1 && t == 255) offs[N_NODES] = base + red[255];
}

// ---------------- fill CSR (lean: no LDS, max occupancy) ----------------

__global__ void fill_csr_kernel(const int* __restrict__ src, const int* __restrict__ dst,
                                const int* __restrict__ offs, int* __restrict__ cnt,
                                int* __restrict__ csr) {
  int e = blockIdx.x * blockDim.x + threadIdx.x;
  if (e < N_EDGES) {
    int d = dst[e];
    int pos = offs[d] + atomicAdd(&cnt[d], 1);
    csr[pos] = src[e];
  }
}

// ---------------- psi layer 0: [Ab(bf16) | Bb(fp8)] = X @ Wf[128x256] ----------------

__global__ __launch_bounds__(256, 3) void gemm_psi0(const u16* __restrict__ X0,
                                                    const u16* __restrict__ Wf,
                                                    const float* __restrict__ bias,
                                                    u16* __restrict__ Ab, u8* __restrict__ Bb) {
  __shared__ u16 Xs[64][72];
  __shared__ u16 Ws[256][72];
  const int tid = threadIdx.x;
  const int row0 = blockIdx.x * 64;
  const int w = tid >> 6, lane = tid & 63;
  const int lm = lane & 15, lq = lane >> 4;

  f32x4 acc[16];
#pragma unroll
  for (int i = 0; i < 16; ++i) acc[i] = (f32x4){0.f, 0.f, 0.f, 0.f};

#pragma unroll
  for (int c = 0; c < 2; ++c) {
#pragma unroll
    for (int i = 0; i < 2; ++i) {
      int fi = tid + i * 256;
      int r = fi >> 3, k8 = (fi & 7) * 8;
      *(u16x8*)&Xs[r][k8] = *(const u16x8*)(X0 + (size_t)(row0 + r) * DD + c * 64 + k8);
    }
#pragma unroll
    for (int i = 0; i < 8; ++i) {
      int fi = tid + i * 256;
      int n = fi >> 3, k8 = (fi & 7) * 8;
      *(u16x8*)&Ws[n][k8] = *(const u16x8*)(Wf + (size_t)n * 128 + c * 64 + k8);
    }
    __syncthreads();
#pragma unroll
    for (int ks = 0; ks < 2; ++ks) {
      bf16x8 a = *(const bf16x8*)&Xs[w * 16 + lm][lq * 8 + ks * 32];
#pragma unroll
      for (int nt = 0; nt < 16; ++nt) {
        bf16x8 b = *(const bf16x8*)&Ws[nt * 16 + lm][lq * 8 + ks * 32];
        acc[nt] = __builtin_amdgcn_mfma_f32_16x16x32_bf16(a, b, acc[nt], 0, 0, 0);
      }
    }
    __syncthreads();
  }

  float bj[8];
#pragma unroll
  for (int nt = 0; nt < 8; ++nt) bj[nt] = bias[nt * 16 + lm];
#pragma unroll
  for (int r = 0; r < 4; ++r) {
    size_t grow = (size_t)(row0 + w * 16 + lq * 4 + r) * DD;
#pragma unroll
    for (int nt = 0; nt < 8; ++nt) Ab[grow + nt * 16 + lm] = f2bf(acc[nt][r] + bj[nt]);
#pragma unroll
    for (int nt = 0; nt < 8; ++nt) Bb[grow + nt * 16 + lm] = f2fp8(acc[nt + 8][r]);
  }
}

// ---------------- aggregation (fp8 B, channel-split halves for L2 residency) ----------------
// Two waves per node (one per 64-channel half; half-table = 2.6 MB -> fits per-XCD L2).
// Wave = 4 groups x 16 lanes; group owns edge slot (stride 4), lane = 4 channels (u32).
// 16 edges in flight per wave-iter; sentinel row (-448) masks tail; 2 shfl_xor to combine.

__global__ __launch_bounds__(256) void aggregate_fp8(
    const u16* __restrict__ A, const u8* __restrict__ B, const int* __restrict__ offs,
    const int* __restrict__ csr, const float* __restrict__ inv_deg, u16* __restrict__ agg) {
  int b = blockIdx.x;
  int half = (b >= 10000) ? 1 : 0;
  int nb = b - half * 10000;
  int node = nb * 4 + (threadIdx.x >> 6);
  int lane = threadIdx.x & 63;
  int grp = lane >> 4;       // edge slot 0..3
  int li = lane & 15;        // channel lane
  int c4 = half * 64 + li * 4;

  uint2 au = *(const uint2*)(A + (size_t)node * DD + c4);
  float a0 = bflo2f(au.x), a1 = bfhi2f(au.x), a2 = bflo2f(au.y), a3 = bfhi2f(au.y);
  int e = offs[node], ee = offs[node + 1];
  float s0 = 0.f, s1 = 0.f, s2 = 0.f, s3 = 0.f;

  for (int cur = e + grp; cur < ee; cur += 16) {
    int idx[4];
#pragma unroll
    for (int i = 0; i < 4; ++i) {
      int t = cur + 4 * i;
      int v = csr[t];  // csr padded with 16 sentinels past N_EDGES
      idx[i] = (t < ee) ? v : N_NODES;  // sentinel row = -448 -> relu contributes 0
    }
    uint32_t bv[4];
#pragma unroll
    for (int i = 0; i < 4; ++i) bv[i] = *(const uint32_t*)(B + (size_t)idx[i] * DD + c4);
#pragma unroll
    for (int i = 0; i < 4; ++i) {
      s0 += fmaxf(a0 + __builtin_amdgcn_cvt_f32_fp8(bv[i], 0), 0.f);
      s1 += fmaxf(a1 + __builtin_amdgcn_cvt_f32_fp8(bv[i], 1), 0.f);
      s2 += fmaxf(a2 + __builtin_amdgcn_cvt_f32_fp8(bv[i], 2), 0.f);
      s3 += fmaxf(a3 + __builtin_amdgcn_cvt_f32_fp8(bv[i], 3), 0.f);
    }
  }
  // combine the 4 edge-groups (lanes with equal li)
  s0 += __shfl_xor(s0, 16); s1 += __shfl_xor(s1, 16);
  s2 += __shfl_xor(s2, 16); s3 += __shfl_xor(s3, 16);
  s0 += __shfl_xor(s0, 32); s1 += __shfl_xor(s1, 32);
  s2 += __shfl_xor(s2, 32); s3 += __shfl_xor(s3, 32);
  if (grp == 0) {
    float wg = inv_deg[node];
    uint2 o;
    o.x = (uint32_t)f2bf(s0 * wg) | ((uint32_t)f2bf(s1 * wg) << 16);
    o.y = (uint32_t)f2bf(s2 * wg) | ((uint32_t)f2bf(s3 * wg) << 16);
    *(uint2*)(agg + (size_t)node * DD + c4) = o;
  }
}

// ---------------- phi GEMM (K=256: x|agg) + residual, h kept in LDS;
// then: !LAST -> psi_{l+1} GEMM (2 halves, K=128 from LDS h) -> Ab(bf16)/Bb(fp8)
//        LAST -> dp GEMM (K=128 from LDS h) -> fp32 out

template <bool LAST>
__global__ __launch_bounds__(256, 3) void phi_psi(
    const u16* __restrict__ X0, const u16* __restrict__ X1, const u16* __restrict__ Wt,
    const float* __restrict__ bias, const u16* __restrict__ WN,
    const float* __restrict__ bN, u16* __restrict__ outB, u16* __restrict__ Ab,
    u8* __restrict__ Bb, float* __restrict__ outF) {
  __shared__ u16 Xs[2][64][72];
  __shared__ u16 Ws[128][72];
  const int tid = threadIdx.x;
  const int row0 = blockIdx.x * 64;
  const int w = tid >> 6, lane = tid & 63;
  const int lm = lane & 15, lq = lane >> 4;

  f32x4 acc[8];
#pragma unroll
  for (int i = 0; i < 8; ++i) acc[i] = (f32x4){0.f, 0.f, 0.f, 0.f};

#pragma unroll
  for (int c = 0; c < 4; ++c) {
    const u16* Xsrc = (c < 2) ? (X0 + c * 64) : (X1 + (c - 2) * 64);
#pragma unroll
    for (int i = 0; i < 2; ++i) {
      int fi = tid + i * 256;
      int r = fi >> 3, k8 = (fi & 7) * 8;
      *(u16x8*)&Xs[c & 1][r][k8] = *(const u16x8*)(Xsrc + (size_t)(row0 + r) * DD + k8);
    }
#pragma unroll
    for (int i = 0; i < 4; ++i) {
      int fi = tid + i * 256;
      int n = fi >> 3, k8 = (fi & 7) * 8;
      *(u16x8*)&Ws[n][k8] = *(const u16x8*)(Wt + (size_t)n * 256 + c * 64 + k8);
    }
    __syncthreads();
#pragma unroll
    for (int ks = 0; ks < 2; ++ks) {
      bf16x8 a = *(const bf16x8*)&Xs[c & 1][w * 16 + lm][lq * 8 + ks * 32];
#pragma unroll
      for (int nt = 0; nt < 8; ++nt) {
        bf16x8 b = *(const bf16x8*)&Ws[nt * 16 + lm][lq * 8 + ks * 32];
        acc[nt] = __builtin_amdgcn_mfma_f32_16x16x32_bf16(a, b, acc[nt], 0, 0, 0);
      }
    }
    __syncthreads();
  }

  // epilogue: v = relu(acc + bias) + x; h tile -> LDS Xs; global xn write only if !LAST
  float bj[8];
#pragma unroll
  for (int nt = 0; nt < 8; ++nt) bj[nt] = bias[nt * 16 + lm];
#pragma unroll
  for (int r = 0; r < 4; ++r) {
    int lrow = w * 16 + lq * 4 + r;
    size_t grow = (size_t)(row0 + lrow) * DD;
#pragma unroll
    for (int nt = 0; nt < 8; ++nt) {
      float res = bflo2f((uint32_t)X0[grow + nt * 16 + lm]);
      float v = fmaxf(acc[nt][r] + bj[nt], 0.f) + res;
      u16 hb = f2bf(v);
      Xs[nt >> 2][lrow][(nt & 3) * 16 + lm] = hb;
      if (!LAST) outB[grow + nt * 16 + lm] = hb;
    }
  }
  __syncthreads();

  if (!LAST) {
    // psi_{l+1}: [Ab|Bb] = h @ WN[256x128], two N-halves of 128
#pragma unroll
    for (int hf = 0; hf < 2; ++hf) {
      f32x4 acc2[8];
#pragma unroll
      for (int i = 0; i < 8; ++i) acc2[i] = (f32x4){0.f, 0.f, 0.f, 0.f};
#pragma unroll
      for (int c = 0; c < 2; ++c) {
#pragma unroll
        for (int i = 0; i < 4; ++i) {
          int fi = tid + i * 256;
          int n = fi >> 3, k8 = (fi & 7) * 8;
          *(u16x8*)&Ws[n][k8] =
              *(const u16x8*)(WN + (size_t)(hf * 128 + n) * DD + c * 64 + k8);
        }
        __syncthreads();
#pragma unroll
        for (int ks = 0; ks < 2; ++ks) {
          bf16x8 a = *(const bf16x8*)&Xs[c][w * 16 + lm][lq * 8 + ks * 32];
#pragma unroll
          for (int nt = 0; nt < 8; ++nt) {
            bf16x8 b = *(const bf16x8*)&Ws[nt * 16 + lm][lq * 8 + ks * 32];
            acc2[nt] = __builtin_amdgcn_mfma_f32_16x16x32_bf16(a, b, acc2[nt], 0, 0, 0);
          }
        }
        __syncthreads();
      }
      if (hf == 0) {
        float b2[8];
#pragma unroll
        for (int nt = 0; nt < 8; ++nt) b2[nt] = bN[nt * 16 + lm];
#pragma unroll
        for (int r = 0; r < 4; ++r) {
          size_t grow = (size_t)(row0 + w * 16 + lq * 4 + r) * DD;
#pragma unroll
          for (int nt = 0; nt < 8; ++nt)
            Ab[grow + nt * 16 + lm] = f2bf(acc2[nt][r] + b2[nt]);
        }
      } else {
#pragma unroll
        for (int r = 0; r < 4; ++r) {
          size_t grow = (size_t)(row0 + w * 16 + lq * 4 + r) * DD;
#pragma unroll
          for (int nt = 0; nt < 8; ++nt) Bb[grow + nt * 16 + lm] = f2fp8(acc2[nt][r]);
        }
      }
    }
  } else {
    // dp: out = h @ WN[128x128] + bN (fp32)
    f32x4 acc2[8];
#pragma unroll
    for (int i = 0; i < 8; ++i) acc2[i] = (f32x4){0.f, 0.f, 0.f, 0.f};
#pragma unroll
    for (int c = 0; c < 2; ++c) {
#pragma unroll
      for (int i = 0; i < 4; ++i) {
        int fi = tid + i * 256;
        int n = fi >> 3, k8 = (fi & 7) * 8;
        *(u16x8*)&Ws[n][k8] = *(const u16x8*)(WN + (size_t)n * DD + c * 64 + k8);
      }
      __syncthreads();
#pragma unroll
      for (int ks = 0; ks < 2; ++ks) {
        bf16x8 a = *(const bf16x8*)&Xs[c][w * 16 + lm][lq * 8 + ks * 32];
#pragma unroll
        for (int nt = 0; nt < 8; ++nt) {
          bf16x8 b = *(const bf16x8*)&Ws[nt * 16 + lm][lq * 8 + ks * 32];
          acc2[nt] = __builtin_amdgcn_mfma_f32_16x16x32_bf16(a, b, acc2[nt], 0, 0, 0);
        }
      }
      __syncthreads();
    }
    float dj[8];
#pragma unroll
    for (int nt = 0; nt < 8; ++nt) dj[nt] = bN[nt * 16 + lm];
#pragma unroll
    for (int r = 0; r < 4; ++r) {
      size_t grow = (size_t)(row0 + w * 16 + lq * 4 + r) * DD;
#pragma unroll
      for (int nt = 0; nt < 8; ++nt) outF[grow + nt * 16 + lm] = acc2[nt][r] + dj[nt];
    }
  }
}

// ---------------- launch ----------------

static inline char* align256(char* p) {
  return (char*)(((uintptr_t)p + 255) & ~(uintptr_t)255);
}

extern "C" void kernel_launch(void* const* d_in, const int* in_sizes, int n_in,
                              void* d_out, int out_size, void* d_ws, size_t ws_size,
                              hipStream_t stream) {
  const float* x_in  = (const float*)d_in[0];
  const int*   ei    = (const int*)d_in[1];
  const float* psi_w = (const float*)d_in[2];
  const float* psi_b = (const float*)d_in[3];
  const float* phi_w = (const float*)d_in[4];
  const float* phi_b = (const float*)d_in[5];
  const float* dp_w  = (const float*)d_in[6];
  const float* dp_b  = (const float*)d_in[7];
  float* out = (float*)d_out;

  const int* e_src = ei;
  const int* e_dst = ei + N_EDGES;

  const size_t NF = (size_t)N_NODES * DD;

  char* p = (char*)d_ws;
  int* deg = (int*)p;         p += N_NODES * sizeof(int);
  int* cnt = (int*)p;         p = align256(p + N_NODES * sizeof(int));
  int* offs = (int*)p;        p = align256(p + (N_NODES + 1) * sizeof(int));
  int* csr = (int*)p;         p = align256(p + (N_EDGES + 16) * sizeof(int));
  float* inv_deg = (float*)p; p = align256(p + N_NODES * sizeof(float));
  u16* xb0 = (u16*)p;         p = align256(p + NF * sizeof(u16));
  u16* xb1 = (u16*)p;         p = align256(p + NF * sizeof(u16));
  u16* Ab = (u16*)p;          p = align256(p + NF * sizeof(u16));
  u8* Bb = (u8*)p;            p = align256(p + (NF + DD) * sizeof(u8));  // +1 sentinel row
  u16* aggb = (u16*)p;        p = align256(p + NF * sizeof(u16));
  u16* psiF = (u16*)p;        p = align256(p + 3 * 256 * 128 * sizeof(u16));
  u16* phiT = (u16*)p;        p = align256(p + 3 * 128 * 256 * sizeof(u16));
  u16* dpT = (u16*)p;         p = align256(p + 128 * 128 * sizeof(u16));

  hipMemsetAsync(deg, 0, 2 * N_NODES * sizeof(int), stream);  // deg + cnt contiguous

  setup_kernel<<<5833, 256, 0, stream>>>(x_in, psi_w, phi_w, dp_w, e_dst, xb0, psiF, phiT,
                                         dpT, deg, Bb);
  scan_all<<<SB, 256, 0, stream>>>(deg, offs, inv_deg, csr);
  fill_csr_kernel<<<(N_EDGES + 255) / 256, 256, 0, stream>>>(e_src, e_dst, offs, cnt, csr);

  const int GB = N_NODES / 64;  // 625 blocks

  gemm_psi0<<<GB, 256, 0, stream>>>(xb0, psiF, psi_b, Ab, Bb);

  u16* xbc = xb0;
  u16* xbn = xb1;
  for (int l = 0; l < LAYERS; ++l) {
    aggregate_fp8<<<20000, 256, 0, stream>>>(Ab, Bb, offs, csr, inv_deg, aggb);
    if (l < LAYERS - 1) {
      phi_psi<false><<<GB, 256, 0, stream>>>(
          xbc, aggb, phiT + (size_t)l * 32768, phi_b + l * DD,
          psiF + (size_t)(l + 1) * 32768, psi_b + (l + 1) * DD, xbn, Ab, Bb, nullptr);
    } else {
      phi_psi<true><<<GB, 256, 0, stream>>>(
          xbc, aggb, phiT + (size_t)l * 32768, phi_b + l * DD, dpT, dp_b, nullptr,
          nullptr, nullptr, out);
    }
    u16* t = xbc; xbc = xbn; xbn = t;
  }
}

// Round 10
// 289.809 us; speedup vs baseline: 1.0792x; 1.0792x over previous
//
#include <hip/hip_runtime.h>
#include <stdint.h>

#define N_NODES 40000
#define N_EDGES 640000
#define DD 128
#define LAYERS 3
#define SB 40  // scan blocks: 40 * 1024 >= N_NODES

typedef unsigned short u16;
typedef unsigned char u8;
typedef u16 u16x8 __attribute__((ext_vector_type(8)));
typedef short bf16x8 __attribute__((ext_vector_type(8)));
typedef float f32x4 __attribute__((ext_vector_type(4)));

__device__ inline u16 f2bf(float f) {  // RNE f32 -> bf16 (finite inputs)
  uint32_t u = __float_as_uint(f);
  return (u16)((u + 0x7fffu + ((u >> 16) & 1u)) >> 16);
}
__device__ inline float bflo2f(uint32_t u) { return __uint_as_float(u << 16); }
__device__ inline float bfhi2f(uint32_t u) { return __uint_as_float(u & 0xffff0000u); }
__device__ inline u8 f2fp8(float f) {  // f32 -> OCP e4m3fn via HW cvt
  return (u8)(__builtin_amdgcn_cvt_pk_fp8_f32(f, f, 0, false) & 0xFF);
}

// ---------------- setup: convert x, convert weights, count degrees, B sentinel ----------------
// psiF: [l][o=256][k=128]; phiT: [l][n=128][k=256]; dpT: [n=128][k=128]

__global__ __launch_bounds__(256) void setup_kernel(
    const float* __restrict__ x, const float* __restrict__ psi_w,
    const float* __restrict__ phi_w, const float* __restrict__ dp_w,
    const int* __restrict__ dst, u16* __restrict__ xb, u16* __restrict__ psiF,
    u16* __restrict__ phiT, u16* __restrict__ dpT, int* __restrict__ deg,
    u8* __restrict__ Bb) {
  int b = blockIdx.x, t = threadIdx.x;
  if (b < 2500) {  // convert x: 2500*256*8 = 5.12M elements
    size_t i = ((size_t)b * 256 + t) * 8;
    float4 v0 = *(const float4*)(x + i);
    float4 v1 = *(const float4*)(x + i + 4);
    u16x8 o;
    o[0] = f2bf(v0.x); o[1] = f2bf(v0.y); o[2] = f2bf(v0.z); o[3] = f2bf(v0.w);
    o[4] = f2bf(v1.x); o[5] = f2bf(v1.y); o[6] = f2bf(v1.z); o[7] = f2bf(v1.w);
    *(u16x8*)(xb + i) = o;
  } else if (b < 3332) {  // weights: 832*256 = 212992
    int idx = (b - 2500) * 256 + t;
    if (idx < 98304) {
      int l = idx >> 15, r = idx & 32767, o = r >> 7, k = r & 127;
      int kk = k + ((o >= 128) ? 128 : 0);
      psiF[idx] = f2bf(psi_w[l * 32768 + kk * 128 + (o & 127)]);
    } else if (idx < 196608) {
      int j = idx - 98304;
      int l = j >> 15, r = j & 32767, n = r >> 8, k = r & 255;
      phiT[j] = f2bf(phi_w[l * 32768 + k * 128 + n]);
    } else {
      int j = idx - 196608;
      int n = j >> 7, k = j & 127;
      dpT[j] = f2bf(dp_w[k * 128 + n]);
    }
  } else if (b < 5832) {  // count degrees: 2500*256 = 640000
    int e = (b - 3332) * 256 + t;
    atomicAdd(&deg[dst[e]], 1);
  } else {  // sentinel row: Bb[N_NODES][*] = 0xFE (-448 in e4m3fn) -> relu(A-448)=0
    if (t < 32) ((uint32_t*)(Bb + (size_t)N_NODES * DD))[t] = 0xFEFEFEFEu;
  }
}

// ---------------- scan (single dispatch): each block self-computes its prefix base ----------

__global__ __launch_bounds__(256) void scan_all(const int* __restrict__ deg,
                                                int* __restrict__ offs,
                                                float* __restrict__ inv_deg,
                                                int* __restrict__ csr) {
  __shared__ int red[256];
  int b = blockIdx.x, t = threadIdx.x;
  if (b == 0 && t < 32) csr[N_EDGES + t] = N_NODES;  // sentinel pad for batched gather
  int base_n = b * 1024;
  int loc = 0;
  for (int i = t * 4; i < base_n; i += 1024) {
    int4 v = *(const int4*)(deg + i);
    loc += v.x + v.y + v.z + v.w;
  }
  red[t] = loc;
  __syncthreads();
  for (int o = 128; o > 0; o >>= 1) {
    if (t < o) red[t] += red[t + o];
    __syncthreads();
  }
  int base = red[0];
  __syncthreads();
  int idx = base_n + t * 4;
  int4 v = {0, 0, 0, 0};
  if (idx < N_NODES) v = *(const int4*)(deg + idx);
  int ts = v.x + v.y + v.z + v.w;
  red[t] = ts;
  __syncthreads();
  for (int o = 1; o < 256; o <<= 1) {
    int u = (t >= o) ? red[t - o] : 0;
    __syncthreads();
    red[t] += u;
    __syncthreads();
  }
  int excl = base + red[t] - ts;
  if (idx < N_NODES) {
    int4 ov;
    ov.x = excl;
    ov.y = excl + v.x;
    ov.z = ov.y + v.y;
    ov.w = ov.z + v.z;
    *(int4*)(offs + idx) = ov;
    float4 iv;
    iv.x = 1.0f / (float)(v.x > 1 ? v.x : 1);
    iv.y = 1.0f / (float)(v.y > 1 ? v.y : 1);
    iv.z = 1.0f / (float)(v.z > 1 ? v.z : 1);
    iv.w = 1.0f / (float)(v.w > 1 ? v.w : 1);
    *(float4*)(inv_deg + idx) = iv;
  }
  if (b == SB - 1 && t == 255) offs[N_NODES] = base + red[255];
}

// ---------------- fill CSR (lean: no LDS, max occupancy) ----------------

__global__ void fill_csr_kernel(const int* __restrict__ src, const int* __restrict__ dst,
                                const int* __restrict__ offs, int* __restrict__ cnt,
                                int* __restrict__ csr) {
  int e = blockIdx.x * blockDim.x + threadIdx.x;
  if (e < N_EDGES) {
    int d = dst[e];
    int pos = offs[d] + atomicAdd(&cnt[d], 1);
    csr[pos] = src[e];
  }
}

// ---------------- psi layer 0: [Ab(bf16) | Bb(fp8)] = X @ Wf[128x256] ----------------

__global__ __launch_bounds__(256, 3) void gemm_psi0(const u16* __restrict__ X0,
                                                    const u16* __restrict__ Wf,
                                                    const float* __restrict__ bias,
                                                    u16* __restrict__ Ab, u8* __restrict__ Bb) {
  __shared__ u16 Xs[64][72];
  __shared__ u16 Ws[256][72];
  const int tid = threadIdx.x;
  const int row0 = blockIdx.x * 64;
  const int w = tid >> 6, lane = tid & 63;
  const int lm = lane & 15, lq = lane >> 4;

  f32x4 acc[16];
#pragma unroll
  for (int i = 0; i < 16; ++i) acc[i] = (f32x4){0.f, 0.f, 0.f, 0.f};

#pragma unroll
  for (int c = 0; c < 2; ++c) {
#pragma unroll
    for (int i = 0; i < 2; ++i) {
      int fi = tid + i * 256;
      int r = fi >> 3, k8 = (fi & 7) * 8;
      *(u16x8*)&Xs[r][k8] = *(const u16x8*)(X0 + (size_t)(row0 + r) * DD + c * 64 + k8);
    }
#pragma unroll
    for (int i = 0; i < 8; ++i) {
      int fi = tid + i * 256;
      int n = fi >> 3, k8 = (fi & 7) * 8;
      *(u16x8*)&Ws[n][k8] = *(const u16x8*)(Wf + (size_t)n * 128 + c * 64 + k8);
    }
    __syncthreads();
#pragma unroll
    for (int ks = 0; ks < 2; ++ks) {
      bf16x8 a = *(const bf16x8*)&Xs[w * 16 + lm][lq * 8 + ks * 32];
#pragma unroll
      for (int nt = 0; nt < 16; ++nt) {
        bf16x8 b = *(const bf16x8*)&Ws[nt * 16 + lm][lq * 8 + ks * 32];
        acc[nt] = __builtin_amdgcn_mfma_f32_16x16x32_bf16(a, b, acc[nt], 0, 0, 0);
      }
    }
    __syncthreads();
  }

  float bj[8];
#pragma unroll
  for (int nt = 0; nt < 8; ++nt) bj[nt] = bias[nt * 16 + lm];
#pragma unroll
  for (int r = 0; r < 4; ++r) {
    size_t grow = (size_t)(row0 + w * 16 + lq * 4 + r) * DD;
#pragma unroll
    for (int nt = 0; nt < 8; ++nt) Ab[grow + nt * 16 + lm] = f2bf(acc[nt][r] + bj[nt]);
#pragma unroll
    for (int nt = 0; nt < 8; ++nt) Bb[grow + nt * 16 + lm] = f2fp8(acc[nt + 8][r]);
  }
}

// ---------------- aggregation (fp8 B): one wave/node, half-wave/edge, lane = 4 channels ----
// batch-16 deep pipeline: 16 idx loads then 16 row-gathers in flight per half-wave;
// mean degree 16 -> most nodes complete in ONE dependent round. Sentinel tail masking.

__global__ __launch_bounds__(256) void aggregate_fp8(
    const u16* __restrict__ A, const u8* __restrict__ B, const int* __restrict__ offs,
    const int* __restrict__ csr, const float* __restrict__ inv_deg, u16* __restrict__ agg) {
  int node = blockIdx.x * 4 + (threadIdx.x >> 6);
  int lane = threadIdx.x & 63;
  int half = lane >> 5;        // which edge of the interleaved pair
  int c4 = (lane & 31) * 4;    // 4 channels
  uint2 au = *(const uint2*)(A + (size_t)node * DD + c4);
  float a0 = bflo2f(au.x), a1 = bfhi2f(au.x), a2 = bflo2f(au.y), a3 = bfhi2f(au.y);
  int e = offs[node], ee = offs[node + 1];
  float s0 = 0.f, s1 = 0.f, s2 = 0.f, s3 = 0.f;
  for (int base = e + half; base < ee; base += 32) {
    int idx[16];
#pragma unroll
    for (int i = 0; i < 16; ++i) {
      int t = base + 2 * i;
      int v = csr[t];  // csr padded with 32 sentinels past N_EDGES
      idx[i] = (t < ee) ? v : N_NODES;  // sentinel row = -448 -> relu contributes 0
    }
    uint32_t bv[16];
#pragma unroll
    for (int i = 0; i < 16; ++i) bv[i] = *(const uint32_t*)(B + (size_t)idx[i] * DD + c4);
#pragma unroll
    for (int i = 0; i < 16; ++i) {
      s0 += fmaxf(a0 + __builtin_amdgcn_cvt_f32_fp8(bv[i], 0), 0.f);
      s1 += fmaxf(a1 + __builtin_amdgcn_cvt_f32_fp8(bv[i], 1), 0.f);
      s2 += fmaxf(a2 + __builtin_amdgcn_cvt_f32_fp8(bv[i], 2), 0.f);
      s3 += fmaxf(a3 + __builtin_amdgcn_cvt_f32_fp8(bv[i], 3), 0.f);
    }
  }
  s0 += __shfl_xor(s0, 32);
  s1 += __shfl_xor(s1, 32);
  s2 += __shfl_xor(s2, 32);
  s3 += __shfl_xor(s3, 32);
  if (half == 0) {
    float wg = inv_deg[node];
    uint2 o;
    o.x = (uint32_t)f2bf(s0 * wg) | ((uint32_t)f2bf(s1 * wg) << 16);
    o.y = (uint32_t)f2bf(s2 * wg) | ((uint32_t)f2bf(s3 * wg) << 16);
    *(uint2*)(agg + (size_t)node * DD + c4) = o;
  }
}

// ---------------- phi GEMM (K=256: x|agg) + residual, h kept in LDS;
// then: !LAST -> psi_{l+1} GEMM (2 halves, K=128 from LDS h) -> Ab(bf16)/Bb(fp8)
//        LAST -> dp GEMM (K=128 from LDS h) -> fp32 out

template <bool LAST>
__global__ __launch_bounds__(256, 3) void phi_psi(
    const u16* __restrict__ X0, const u16* __restrict__ X1, const u16* __restrict__ Wt,
    const float* __restrict__ bias, const u16* __restrict__ WN,
    const float* __restrict__ bN, u16* __restrict__ outB, u16* __restrict__ Ab,
    u8* __restrict__ Bb, float* __restrict__ outF) {
  __shared__ u16 Xs[2][64][72];
  __shared__ u16 Ws[128][72];
  const int tid = threadIdx.x;
  const int row0 = blockIdx.x * 64;
  const int w = tid >> 6, lane = tid & 63;
  const int lm = lane & 15, lq = lane >> 4;

  f32x4 acc[8];
#pragma unroll
  for (int i = 0; i < 8; ++i) acc[i] = (f32x4){0.f, 0.f, 0.f, 0.f};

#pragma unroll
  for (int c = 0; c < 4; ++c) {
    const u16* Xsrc = (c < 2) ? (X0 + c * 64) : (X1 + (c - 2) * 64);
#pragma unroll
    for (int i = 0; i < 2; ++i) {
      int fi = tid + i * 256;
      int r = fi >> 3, k8 = (fi & 7) * 8;
      *(u16x8*)&Xs[c & 1][r][k8] = *(const u16x8*)(Xsrc + (size_t)(row0 + r) * DD + k8);
    }
#pragma unroll
    for (int i = 0; i < 4; ++i) {
      int fi = tid + i * 256;
      int n = fi >> 3, k8 = (fi & 7) * 8;
      *(u16x8*)&Ws[n][k8] = *(const u16x8*)(Wt + (size_t)n * 256 + c * 64 + k8);
    }
    __syncthreads();
#pragma unroll
    for (int ks = 0; ks < 2; ++ks) {
      bf16x8 a = *(const bf16x8*)&Xs[c & 1][w * 16 + lm][lq * 8 + ks * 32];
#pragma unroll
      for (int nt = 0; nt < 8; ++nt) {
        bf16x8 b = *(const bf16x8*)&Ws[nt * 16 + lm][lq * 8 + ks * 32];
        acc[nt] = __builtin_amdgcn_mfma_f32_16x16x32_bf16(a, b, acc[nt], 0, 0, 0);
      }
    }
    __syncthreads();
  }

  // epilogue: v = relu(acc + bias) + x; h tile -> LDS Xs; global xn write only if !LAST
  float bj[8];
#pragma unroll
  for (int nt = 0; nt < 8; ++nt) bj[nt] = bias[nt * 16 + lm];
#pragma unroll
  for (int r = 0; r < 4; ++r) {
    int lrow = w * 16 + lq * 4 + r;
    size_t grow = (size_t)(row0 + lrow) * DD;
#pragma unroll
    for (int nt = 0; nt < 8; ++nt) {
      float res = bflo2f((uint32_t)X0[grow + nt * 16 + lm]);
      float v = fmaxf(acc[nt][r] + bj[nt], 0.f) + res;
      u16 hb = f2bf(v);
      Xs[nt >> 2][lrow][(nt & 3) * 16 + lm] = hb;
      if (!LAST) outB[grow + nt * 16 + lm] = hb;
    }
  }
  __syncthreads();

  if (!LAST) {
    // psi_{l+1}: [Ab|Bb] = h @ WN[256x128], two N-halves of 128
#pragma unroll
    for (int hf = 0; hf < 2; ++hf) {
      f32x4 acc2[8];
#pragma unroll
      for (int i = 0; i < 8; ++i) acc2[i] = (f32x4){0.f, 0.f, 0.f, 0.f};
#pragma unroll
      for (int c = 0; c < 2; ++c) {
#pragma unroll
        for (int i = 0; i < 4; ++i) {
          int fi = tid + i * 256;
          int n = fi >> 3, k8 = (fi & 7) * 8;
          *(u16x8*)&Ws[n][k8] =
              *(const u16x8*)(WN + (size_t)(hf * 128 + n) * DD + c * 64 + k8);
        }
        __syncthreads();
#pragma unroll
        for (int ks = 0; ks < 2; ++ks) {
          bf16x8 a = *(const bf16x8*)&Xs[c][w * 16 + lm][lq * 8 + ks * 32];
#pragma unroll
          for (int nt = 0; nt < 8; ++nt) {
            bf16x8 b = *(const bf16x8*)&Ws[nt * 16 + lm][lq * 8 + ks * 32];
            acc2[nt] = __builtin_amdgcn_mfma_f32_16x16x32_bf16(a, b, acc2[nt], 0, 0, 0);
          }
        }
        __syncthreads();
      }
      if (hf == 0) {
        float b2[8];
#pragma unroll
        for (int nt = 0; nt < 8; ++nt) b2[nt] = bN[nt * 16 + lm];
#pragma unroll
        for (int r = 0; r < 4; ++r) {
          size_t grow = (size_t)(row0 + w * 16 + lq * 4 + r) * DD;
#pragma unroll
          for (int nt = 0; nt < 8; ++nt)
            Ab[grow + nt * 16 + lm] = f2bf(acc2[nt][r] + b2[nt]);
        }
      } else {
#pragma unroll
        for (int r = 0; r < 4; ++r) {
          size_t grow = (size_t)(row0 + w * 16 + lq * 4 + r) * DD;
#pragma unroll
          for (int nt = 0; nt < 8; ++nt) Bb[grow + nt * 16 + lm] = f2fp8(acc2[nt][r]);
        }
      }
    }
  } else {
    // dp: out = h @ WN[128x128] + bN (fp32)
    f32x4 acc2[8];
#pragma unroll
    for (int i = 0; i < 8; ++i) acc2[i] = (f32x4){0.f, 0.f, 0.f, 0.f};
#pragma unroll
    for (int c = 0; c < 2; ++c) {
#pragma unroll
      for (int i = 0; i < 4; ++i) {
        int fi = tid + i * 256;
        int n = fi >> 3, k8 = (fi & 7) * 8;
        *(u16x8*)&Ws[n][k8] = *(const u16x8*)(WN + (size_t)n * DD + c * 64 + k8);
      }
      __syncthreads();
#pragma unroll
      for (int ks = 0; ks < 2; ++ks) {
        bf16x8 a = *(const bf16x8*)&Xs[c][w * 16 + lm][lq * 8 + ks * 32];
#pragma unroll
        for (int nt = 0; nt < 8; ++nt) {
          bf16x8 b = *(const bf16x8*)&Ws[nt * 16 + lm][lq * 8 + ks * 32];
          acc2[nt] = __builtin_amdgcn_mfma_f32_16x16x32_bf16(a, b, acc2[nt], 0, 0, 0);
        }
      }
      __syncthreads();
    }
    float dj[8];
#pragma unroll
    for (int nt = 0; nt < 8; ++nt) dj[nt] = bN[nt * 16 + lm];
#pragma unroll
    for (int r = 0; r < 4; ++r) {
      size_t grow = (size_t)(row0 + w * 16 + lq * 4 + r) * DD;
#pragma unroll
      for (int nt = 0; nt < 8; ++nt) outF[grow + nt * 16 + lm] = acc2[nt][r] + dj[nt];
    }
  }
}

// ---------------- launch ----------------

static inline char* align256(char* p) {
  return (char*)(((uintptr_t)p + 255) & ~(uintptr_t)255);
}

extern "C" void kernel_launch(void* const* d_in, const int* in_sizes, int n_in,
                              void* d_out, int out_size, void* d_ws, size_t ws_size,
                              hipStream_t stream) {
  const float* x_in  = (const float*)d_in[0];
  const int*   ei    = (const int*)d_in[1];
  const float* psi_w = (const float*)d_in[2];
  const float* psi_b = (const float*)d_in[3];
  const float* phi_w = (const float*)d_in[4];
  const float* phi_b = (const float*)d_in[5];
  const float* dp_w  = (const float*)d_in[6];
  const float* dp_b  = (const float*)d_in[7];
  float* out = (float*)d_out;

  const int* e_src = ei;
  const int* e_dst = ei + N_EDGES;

  const size_t NF = (size_t)N_NODES * DD;

  char* p = (char*)d_ws;
  int* deg = (int*)p;         p += N_NODES * sizeof(int);
  int* cnt = (int*)p;         p = align256(p + N_NODES * sizeof(int));
  int* offs = (int*)p;        p = align256(p + (N_NODES + 1) * sizeof(int));
  int* csr = (int*)p;         p = align256(p + (N_EDGES + 32) * sizeof(int));
  float* inv_deg = (float*)p; p = align256(p + N_NODES * sizeof(float));
  u16* xb0 = (u16*)p;         p = align256(p + NF * sizeof(u16));
  u16* xb1 = (u16*)p;         p = align256(p + NF * sizeof(u16));
  u16* Ab = (u16*)p;          p = align256(p + NF * sizeof(u16));
  u8* Bb = (u8*)p;            p = align256(p + (NF + DD) * sizeof(u8));  // +1 sentinel row
  u16* aggb = (u16*)p;        p = align256(p + NF * sizeof(u16));
  u16* psiF = (u16*)p;        p = align256(p + 3 * 256 * 128 * sizeof(u16));
  u16* phiT = (u16*)p;        p = align256(p + 3 * 128 * 256 * sizeof(u16));
  u16* dpT = (u16*)p;         p = align256(p + 128 * 128 * sizeof(u16));

  hipMemsetAsync(deg, 0, 2 * N_NODES * sizeof(int), stream);  // deg + cnt contiguous

  setup_kernel<<<5833, 256, 0, stream>>>(x_in, psi_w, phi_w, dp_w, e_dst, xb0, psiF, phiT,
                                         dpT, deg, Bb);
  scan_all<<<SB, 256, 0, stream>>>(deg, offs, inv_deg, csr);
  fill_csr_kernel<<<(N_EDGES + 255) / 256, 256, 0, stream>>>(e_src, e_dst, offs, cnt, csr);

  const int GB = N_NODES / 64;  // 625 blocks

  gemm_psi0<<<GB, 256, 0, stream>>>(xb0, psiF, psi_b, Ab, Bb);

  u16* xbc = xb0;
  u16* xbn = xb1;
  for (int l = 0; l < LAYERS; ++l) {
    aggregate_fp8<<<N_NODES / 4, 256, 0, stream>>>(Ab, Bb, offs, csr, inv_deg, aggb);
    if (l < LAYERS - 1) {
      phi_psi<false><<<GB, 256, 0, stream>>>(
          xbc, aggb, phiT + (size_t)l * 32768, phi_b + l * DD,
          psiF + (size_t)(l + 1) * 32768, psi_b + (l + 1) * DD, xbn, Ab, Bb, nullptr);
    } else {
      phi_psi<true><<<GB, 256, 0, stream>>>(
          xbc, aggb, phiT + (size_t)l * 32768, phi_b + l * DD, dpT, dp_b, nullptr,
          nullptr, nullptr, out);
    }
    u16* t = xbc; xbc = xbn; xbn = t;
  }
}

// Round 11
// 257.690 us; speedup vs baseline: 1.2138x; 1.1246x over previous
//
#include <hip/hip_runtime.h>
#include <stdint.h>

#define N_NODES 40000
#define N_EDGES 640000
#define DD 128
#define LAYERS 3
#define SB 40  // scan blocks: 40 * 1024 >= N_NODES

typedef unsigned short u16;
typedef unsigned char u8;
typedef u16 u16x8 __attribute__((ext_vector_type(8)));
typedef short bf16x8 __attribute__((ext_vector_type(8)));
typedef float f32x4 __attribute__((ext_vector_type(4)));

__device__ inline u16 f2bf(float f) {  // RNE f32 -> bf16 (finite inputs)
  uint32_t u = __float_as_uint(f);
  return (u16)((u + 0x7fffu + ((u >> 16) & 1u)) >> 16);
}
__device__ inline float bflo2f(uint32_t u) { return __uint_as_float(u << 16); }
__device__ inline float bfhi2f(uint32_t u) { return __uint_as_float(u & 0xffff0000u); }
__device__ inline u8 f2fp8(float f) {  // f32 -> OCP e4m3fn via HW cvt
  return (u8)(__builtin_amdgcn_cvt_pk_fp8_f32(f, f, 0, false) & 0xFF);
}

// ---------------- setup: convert weights, count degrees (+slot), B sentinel ----------------
// psiF: [l][o=256][k=128]; phiT: [l][n=128][k=256]; dpT: [n=128][k=128]

__global__ __launch_bounds__(256) void setup_kernel(
    const float* __restrict__ psi_w, const float* __restrict__ phi_w,
    const float* __restrict__ dp_w, const int* __restrict__ dst, u16* __restrict__ psiF,
    u16* __restrict__ phiT, u16* __restrict__ dpT, int* __restrict__ deg,
    u16* __restrict__ slot, u8* __restrict__ Bb) {
  int b = blockIdx.x, t = threadIdx.x;
  if (b < 832) {  // weights: 832*256 = 212992
    int idx = b * 256 + t;
    if (idx < 98304) {
      int l = idx >> 15, r = idx & 32767, o = r >> 7, k = r & 127;
      int kk = k + ((o >= 128) ? 128 : 0);
      psiF[idx] = f2bf(psi_w[l * 32768 + kk * 128 + (o & 127)]);
    } else if (idx < 196608) {
      int j = idx - 98304;
      int l = j >> 15, r = j & 32767, n = r >> 8, k = r & 255;
      phiT[j] = f2bf(phi_w[l * 32768 + k * 128 + n]);
    } else if (idx < 212992) {
      int j = idx - 196608;
      int n = j >> 7, k = j & 127;
      dpT[j] = f2bf(dp_w[k * 128 + n]);
    }
  } else if (b < 3332) {  // count degrees + record slot: 2500*256 = 640000
    int e = (b - 832) * 256 + t;
    slot[e] = (u16)atomicAdd(&deg[dst[e]], 1);
  } else {  // sentinel row: Bb[N_NODES][*] = 0xFE (-448 in e4m3fn) -> relu(A-448)=0
    if (t < 32) ((uint32_t*)(Bb + (size_t)N_NODES * DD))[t] = 0xFEFEFEFEu;
  }
}

// ---------------- scan (single dispatch): each block self-computes its prefix base ----------

__global__ __launch_bounds__(256) void scan_all(const int* __restrict__ deg,
                                                int* __restrict__ offs,
                                                float* __restrict__ inv_deg,
                                                int* __restrict__ csr) {
  __shared__ int red[256];
  int b = blockIdx.x, t = threadIdx.x;
  if (b == 0 && t < 32) csr[N_EDGES + t] = N_NODES;  // sentinel pad for batched gather
  int base_n = b * 1024;
  int loc = 0;
  for (int i = t * 4; i < base_n; i += 1024) {
    int4 v = *(const int4*)(deg + i);
    loc += v.x + v.y + v.z + v.w;
  }
  red[t] = loc;
  __syncthreads();
  for (int o = 128; o > 0; o >>= 1) {
    if (t < o) red[t] += red[t + o];
    __syncthreads();
  }
  int base = red[0];
  __syncthreads();
  int idx = base_n + t * 4;
  int4 v = {0, 0, 0, 0};
  if (idx < N_NODES) v = *(const int4*)(deg + idx);
  int ts = v.x + v.y + v.z + v.w;
  red[t] = ts;
  __syncthreads();
  for (int o = 1; o < 256; o <<= 1) {
    int u = (t >= o) ? red[t - o] : 0;
    __syncthreads();
    red[t] += u;
    __syncthreads();
  }
  int excl = base + red[t] - ts;
  if (idx < N_NODES) {
    int4 ov;
    ov.x = excl;
    ov.y = excl + v.x;
    ov.z = ov.y + v.y;
    ov.w = ov.z + v.z;
    *(int4*)(offs + idx) = ov;
    float4 iv;
    iv.x = 1.0f / (float)(v.x > 1 ? v.x : 1);
    iv.y = 1.0f / (float)(v.y > 1 ? v.y : 1);
    iv.z = 1.0f / (float)(v.z > 1 ? v.z : 1);
    iv.w = 1.0f / (float)(v.w > 1 ? v.w : 1);
    *(float4*)(inv_deg + idx) = iv;
  }
  if (b == SB - 1 && t == 255) offs[N_NODES] = base + red[255];
}

// ---------------- fill CSR (atomic-free: pos = offs[d] + slot[e]) ----------------

__global__ void fill_csr_kernel(const int* __restrict__ src, const int* __restrict__ dst,
                                const int* __restrict__ offs, const u16* __restrict__ slot,
                                int* __restrict__ csr) {
  int e = blockIdx.x * blockDim.x + threadIdx.x;
  if (e < N_EDGES) {
    int d = dst[e];
    csr[offs[d] + (int)slot[e]] = src[e];
  }
}

// ---------------- psi layer 0 (reads fp32 x, emits xb0 bf16 + Ab bf16 + Bb fp8) ----------

__global__ __launch_bounds__(256, 3) void gemm_psi0(const float* __restrict__ X,
                                                    u16* __restrict__ xb,
                                                    const u16* __restrict__ Wf,
                                                    const float* __restrict__ bias,
                                                    u16* __restrict__ Ab, u8* __restrict__ Bb) {
  __shared__ u16 Xs[64][72];
  __shared__ u16 Ws[256][72];
  const int tid = threadIdx.x;
  const int row0 = blockIdx.x * 64;
  const int w = tid >> 6, lane = tid & 63;
  const int lm = lane & 15, lq = lane >> 4;

  f32x4 acc[16];
#pragma unroll
  for (int i = 0; i < 16; ++i) acc[i] = (f32x4){0.f, 0.f, 0.f, 0.f};

#pragma unroll
  for (int c = 0; c < 2; ++c) {
#pragma unroll
    for (int i = 0; i < 2; ++i) {
      int fi = tid + i * 256;
      int r = fi >> 3, k8 = (fi & 7) * 8;
      const float* xs = X + (size_t)(row0 + r) * DD + c * 64 + k8;
      float4 v0 = *(const float4*)xs;
      float4 v1 = *(const float4*)(xs + 4);
      u16x8 o;
      o[0] = f2bf(v0.x); o[1] = f2bf(v0.y); o[2] = f2bf(v0.z); o[3] = f2bf(v0.w);
      o[4] = f2bf(v1.x); o[5] = f2bf(v1.y); o[6] = f2bf(v1.z); o[7] = f2bf(v1.w);
      *(u16x8*)&Xs[r][k8] = o;
      *(u16x8*)(xb + (size_t)(row0 + r) * DD + c * 64 + k8) = o;  // side-product bf16 x
    }
#pragma unroll
    for (int i = 0; i < 8; ++i) {
      int fi = tid + i * 256;
      int n = fi >> 3, k8 = (fi & 7) * 8;
      *(u16x8*)&Ws[n][k8] = *(const u16x8*)(Wf + (size_t)n * 128 + c * 64 + k8);
    }
    __syncthreads();
#pragma unroll
    for (int ks = 0; ks < 2; ++ks) {
      bf16x8 a = *(const bf16x8*)&Xs[w * 16 + lm][lq * 8 + ks * 32];
#pragma unroll
      for (int nt = 0; nt < 16; ++nt) {
        bf16x8 b = *(const bf16x8*)&Ws[nt * 16 + lm][lq * 8 + ks * 32];
        acc[nt] = __builtin_amdgcn_mfma_f32_16x16x32_bf16(a, b, acc[nt], 0, 0, 0);
      }
    }
    __syncthreads();
  }

  float bj[8];
#pragma unroll
  for (int nt = 0; nt < 8; ++nt) bj[nt] = bias[nt * 16 + lm];
#pragma unroll
  for (int r = 0; r < 4; ++r) {
    size_t grow = (size_t)(row0 + w * 16 + lq * 4 + r) * DD;
#pragma unroll
    for (int nt = 0; nt < 8; ++nt) Ab[grow + nt * 16 + lm] = f2bf(acc[nt][r] + bj[nt]);
#pragma unroll
    for (int nt = 0; nt < 8; ++nt) Bb[grow + nt * 16 + lm] = f2fp8(acc[nt + 8][r]);
  }
}

// ---------------- aggregation (fp8 B): one wave/node, half-wave/edge, lane = 4 channels ----
// R8-proven shape: batch-8 per half-wave (16 edge slots/iter ~= mean degree)

__global__ __launch_bounds__(256) void aggregate_fp8(
    const u16* __restrict__ A, const u8* __restrict__ B, const int* __restrict__ offs,
    const int* __restrict__ csr, const float* __restrict__ inv_deg, u16* __restrict__ agg) {
  int node = blockIdx.x * 4 + (threadIdx.x >> 6);
  int lane = threadIdx.x & 63;
  int half = lane >> 5;        // which edge of the pair
  int c4 = (lane & 31) * 4;    // 4 channels
  uint2 au = *(const uint2*)(A + (size_t)node * DD + c4);
  float a0 = bflo2f(au.x), a1 = bfhi2f(au.x), a2 = bflo2f(au.y), a3 = bfhi2f(au.y);
  int e = offs[node], ee = offs[node + 1];
  float s0 = 0.f, s1 = 0.f, s2 = 0.f, s3 = 0.f;
  for (int base = e + half; base < ee; base += 16) {
    int idx[8];
#pragma unroll
    for (int i = 0; i < 8; ++i) {
      int t = base + 2 * i;
      int v = csr[t];  // csr padded with sentinels past N_EDGES
      idx[i] = (t < ee) ? v : N_NODES;  // sentinel row = -448 -> relu contributes 0
    }
    uint32_t bv[8];
#pragma unroll
    for (int i = 0; i < 8; ++i) bv[i] = *(const uint32_t*)(B + (size_t)idx[i] * DD + c4);
#pragma unroll
    for (int i = 0; i < 8; ++i) {
      s0 += fmaxf(a0 + __builtin_amdgcn_cvt_f32_fp8(bv[i], 0), 0.f);
      s1 += fmaxf(a1 + __builtin_amdgcn_cvt_f32_fp8(bv[i], 1), 0.f);
      s2 += fmaxf(a2 + __builtin_amdgcn_cvt_f32_fp8(bv[i], 2), 0.f);
      s3 += fmaxf(a3 + __builtin_amdgcn_cvt_f32_fp8(bv[i], 3), 0.f);
    }
  }
  s0 += __shfl_xor(s0, 32);
  s1 += __shfl_xor(s1, 32);
  s2 += __shfl_xor(s2, 32);
  s3 += __shfl_xor(s3, 32);
  if (half == 0) {
    float wg = inv_deg[node];
    uint2 o;
    o.x = (uint32_t)f2bf(s0 * wg) | ((uint32_t)f2bf(s1 * wg) << 16);
    o.y = (uint32_t)f2bf(s2 * wg) | ((uint32_t)f2bf(s3 * wg) << 16);
    *(uint2*)(agg + (size_t)node * DD + c4) = o;
  }
}

// ---------------- phi GEMM (K=256: x|agg) + residual, h kept in LDS;
// then: !LAST -> psi_{l+1} GEMM (2 halves, K=128 from LDS h) -> Ab(bf16)/Bb(fp8)
//        LAST -> dp GEMM (K=128 from LDS h) -> fp32 out

template <bool LAST>
__global__ __launch_bounds__(256, 3) void phi_psi(
    const u16* __restrict__ X0, const u16* __restrict__ X1, const u16* __restrict__ Wt,
    const float* __restrict__ bias, const u16* __restrict__ WN,
    const float* __restrict__ bN, u16* __restrict__ outB, u16* __restrict__ Ab,
    u8* __restrict__ Bb, float* __restrict__ outF) {
  __shared__ u16 Xs[2][64][72];
  __shared__ u16 Ws[128][72];
  const int tid = threadIdx.x;
  const int row0 = blockIdx.x * 64;
  const int w = tid >> 6, lane = tid & 63;
  const int lm = lane & 15, lq = lane >> 4;

  f32x4 acc[8];
#pragma unroll
  for (int i = 0; i < 8; ++i) acc[i] = (f32x4){0.f, 0.f, 0.f, 0.f};

#pragma unroll
  for (int c = 0; c < 4; ++c) {
    const u16* Xsrc = (c < 2) ? (X0 + c * 64) : (X1 + (c - 2) * 64);
#pragma unroll
    for (int i = 0; i < 2; ++i) {
      int fi = tid + i * 256;
      int r = fi >> 3, k8 = (fi & 7) * 8;
      *(u16x8*)&Xs[c & 1][r][k8] = *(const u16x8*)(Xsrc + (size_t)(row0 + r) * DD + k8);
    }
#pragma unroll
    for (int i = 0; i < 4; ++i) {
      int fi = tid + i * 256;
      int n = fi >> 3, k8 = (fi & 7) * 8;
      *(u16x8*)&Ws[n][k8] = *(const u16x8*)(Wt + (size_t)n * 256 + c * 64 + k8);
    }
    __syncthreads();
#pragma unroll
    for (int ks = 0; ks < 2; ++ks) {
      bf16x8 a = *(const bf16x8*)&Xs[c & 1][w * 16 + lm][lq * 8 + ks * 32];
#pragma unroll
      for (int nt = 0; nt < 8; ++nt) {
        bf16x8 b = *(const bf16x8*)&Ws[nt * 16 + lm][lq * 8 + ks * 32];
        acc[nt] = __builtin_amdgcn_mfma_f32_16x16x32_bf16(a, b, acc[nt], 0, 0, 0);
      }
    }
    __syncthreads();
  }

  // epilogue: v = relu(acc + bias) + x; h tile -> LDS Xs; global xn write only if !LAST
  float bj[8];
#pragma unroll
  for (int nt = 0; nt < 8; ++nt) bj[nt] = bias[nt * 16 + lm];
#pragma unroll
  for (int r = 0; r < 4; ++r) {
    int lrow = w * 16 + lq * 4 + r;
    size_t grow = (size_t)(row0 + lrow) * DD;
#pragma unroll
    for (int nt = 0; nt < 8; ++nt) {
      float res = bflo2f((uint32_t)X0[grow + nt * 16 + lm]);
      float v = fmaxf(acc[nt][r] + bj[nt], 0.f) + res;
      u16 hb = f2bf(v);
      Xs[nt >> 2][lrow][(nt & 3) * 16 + lm] = hb;
      if (!LAST) outB[grow + nt * 16 + lm] = hb;
    }
  }
  __syncthreads();

  if (!LAST) {
    // psi_{l+1}: [Ab|Bb] = h @ WN[256x128], two N-halves of 128
#pragma unroll
    for (int hf = 0; hf < 2; ++hf) {
      f32x4 acc2[8];
#pragma unroll
      for (int i = 0; i < 8; ++i) acc2[i] = (f32x4){0.f, 0.f, 0.f, 0.f};
#pragma unroll
      for (int c = 0; c < 2; ++c) {
#pragma unroll
        for (int i = 0; i < 4; ++i) {
          int fi = tid + i * 256;
          int n = fi >> 3, k8 = (fi & 7) * 8;
          *(u16x8*)&Ws[n][k8] =
              *(const u16x8*)(WN + (size_t)(hf * 128 + n) * DD + c * 64 + k8);
        }
        __syncthreads();
#pragma unroll
        for (int ks = 0; ks < 2; ++ks) {
          bf16x8 a = *(const bf16x8*)&Xs[c][w * 16 + lm][lq * 8 + ks * 32];
#pragma unroll
          for (int nt = 0; nt < 8; ++nt) {
            bf16x8 b = *(const bf16x8*)&Ws[nt * 16 + lm][lq * 8 + ks * 32];
            acc2[nt] = __builtin_amdgcn_mfma_f32_16x16x32_bf16(a, b, acc2[nt], 0, 0, 0);
          }
        }
        __syncthreads();
      }
      if (hf == 0) {
        float b2[8];
#pragma unroll
        for (int nt = 0; nt < 8; ++nt) b2[nt] = bN[nt * 16 + lm];
#pragma unroll
        for (int r = 0; r < 4; ++r) {
          size_t grow = (size_t)(row0 + w * 16 + lq * 4 + r) * DD;
#pragma unroll
          for (int nt = 0; nt < 8; ++nt)
            Ab[grow + nt * 16 + lm] = f2bf(acc2[nt][r] + b2[nt]);
        }
      } else {
#pragma unroll
        for (int r = 0; r < 4; ++r) {
          size_t grow = (size_t)(row0 + w * 16 + lq * 4 + r) * DD;
#pragma unroll
          for (int nt = 0; nt < 8; ++nt) Bb[grow + nt * 16 + lm] = f2fp8(acc2[nt][r]);
        }
      }
    }
  } else {
    // dp: out = h @ WN[128x128] + bN (fp32)
    f32x4 acc2[8];
#pragma unroll
    for (int i = 0; i < 8; ++i) acc2[i] = (f32x4){0.f, 0.f, 0.f, 0.f};
#pragma unroll
    for (int c = 0; c < 2; ++c) {
#pragma unroll
      for (int i = 0; i < 4; ++i) {
        int fi = tid + i * 256;
        int n = fi >> 3, k8 = (fi & 7) * 8;
        *(u16x8*)&Ws[n][k8] = *(const u16x8*)(WN + (size_t)n * DD + c * 64 + k8);
      }
      __syncthreads();
#pragma unroll
      for (int ks = 0; ks < 2; ++ks) {
        bf16x8 a = *(const bf16x8*)&Xs[c][w * 16 + lm][lq * 8 + ks * 32];
#pragma unroll
        for (int nt = 0; nt < 8; ++nt) {
          bf16x8 b = *(const bf16x8*)&Ws[nt * 16 + lm][lq * 8 + ks * 32];
          acc2[nt] = __builtin_amdgcn_mfma_f32_16x16x32_bf16(a, b, acc2[nt], 0, 0, 0);
        }
      }
      __syncthreads();
    }
    float dj[8];
#pragma unroll
    for (int nt = 0; nt < 8; ++nt) dj[nt] = bN[nt * 16 + lm];
#pragma unroll
    for (int r = 0; r < 4; ++r) {
      size_t grow = (size_t)(row0 + w * 16 + lq * 4 + r) * DD;
#pragma unroll
      for (int nt = 0; nt < 8; ++nt) outF[grow + nt * 16 + lm] = acc2[nt][r] + dj[nt];
    }
  }
}

// ---------------- launch ----------------

static inline char* align256(char* p) {
  return (char*)(((uintptr_t)p + 255) & ~(uintptr_t)255);
}

extern "C" void kernel_launch(void* const* d_in, const int* in_sizes, int n_in,
                              void* d_out, int out_size, void* d_ws, size_t ws_size,
                              hipStream_t stream) {
  const float* x_in  = (const float*)d_in[0];
  const int*   ei    = (const int*)d_in[1];
  const float* psi_w = (const float*)d_in[2];
  const float* psi_b = (const float*)d_in[3];
  const float* phi_w = (const float*)d_in[4];
  const float* phi_b = (const float*)d_in[5];
  const float* dp_w  = (const float*)d_in[6];
  const float* dp_b  = (const float*)d_in[7];
  float* out = (float*)d_out;

  const int* e_src = ei;
  const int* e_dst = ei + N_EDGES;

  const size_t NF = (size_t)N_NODES * DD;

  char* p = (char*)d_ws;
  int* deg = (int*)p;         p = align256(p + N_NODES * sizeof(int));
  int* offs = (int*)p;        p = align256(p + (N_NODES + 1) * sizeof(int));
  u16* slot = (u16*)p;        p = align256(p + N_EDGES * sizeof(u16));
  int* csr = (int*)p;         p = align256(p + (N_EDGES + 32) * sizeof(int));
  float* inv_deg = (float*)p; p = align256(p + N_NODES * sizeof(float));
  u16* xb0 = (u16*)p;         p = align256(p + NF * sizeof(u16));
  u16* xb1 = (u16*)p;         p = align256(p + NF * sizeof(u16));
  u16* Ab = (u16*)p;          p = align256(p + NF * sizeof(u16));
  u8* Bb = (u8*)p;            p = align256(p + (NF + DD) * sizeof(u8));  // +1 sentinel row
  u16* aggb = (u16*)p;        p = align256(p + NF * sizeof(u16));
  u16* psiF = (u16*)p;        p = align256(p + 3 * 256 * 128 * sizeof(u16));
  u16* phiT = (u16*)p;        p = align256(p + 3 * 128 * 256 * sizeof(u16));
  u16* dpT = (u16*)p;         p = align256(p + 128 * 128 * sizeof(u16));

  hipMemsetAsync(deg, 0, N_NODES * sizeof(int), stream);

  setup_kernel<<<3333, 256, 0, stream>>>(psi_w, phi_w, dp_w, e_dst, psiF, phiT, dpT, deg,
                                         slot, Bb);
  scan_all<<<SB, 256, 0, stream>>>(deg, offs, inv_deg, csr);
  fill_csr_kernel<<<(N_EDGES + 255) / 256, 256, 0, stream>>>(e_src, e_dst, offs, slot, csr);

  const int GB = N_NODES / 64;  // 625 blocks

  gemm_psi0<<<GB, 256, 0, stream>>>(x_in, xb0, psiF, psi_b, Ab, Bb);

  u16* xbc = xb0;
  u16* xbn = xb1;
  for (int l = 0; l < LAYERS; ++l) {
    aggregate_fp8<<<N_NODES / 4, 256, 0, stream>>>(Ab, Bb, offs, csr, inv_deg, aggb);
    if (l < LAYERS - 1) {
      phi_psi<false><<<GB, 256, 0, stream>>>(
          xbc, aggb, phiT + (size_t)l * 32768, phi_b + l * DD,
          psiF + (size_t)(l + 1) * 32768, psi_b + (l + 1) * DD, xbn, Ab, Bb, nullptr);
    } else {
      phi_psi<true><<<GB, 256, 0, stream>>>(
          xbc, aggb, phiT + (size_t)l * 32768, phi_b + l * DD, dpT, dp_b, nullptr,
          nullptr, nullptr, out);
    }
    u16* t = xbc; xbc = xbn; xbn = t;
  }
}